// Round 1
// baseline (305.117 us; speedup 1.0000x reference)
//
#include <hip/hip_runtime.h>

typedef unsigned long long ull;

constexpr int N  = 500;
constexpr int HW = 60800;   // 200*304
constexpr int NW = 950;     // HW/64 (exact)

// ---------------------------------------------------------------------------
// 1) Binarize + bit-pack: one ballot per 64 consecutive pixels.
__global__ void k_pack(const float* __restrict__ mp, ull* __restrict__ packed) {
    int gid = blockIdx.x * blockDim.x + threadIdx.x;   // exact grid, no guard
    float v = mp[gid];
    ull b = __ballot(v > 0.5f);
    if ((threadIdx.x & 63) == 0) packed[gid >> 6] = b;
}

// ---------------------------------------------------------------------------
// 2) Mask areas via popcount (one wave per instance).
__global__ void k_area(const ull* __restrict__ packed, float* __restrict__ areaOrig) {
    int n = blockIdx.x;
    int lane = threadIdx.x;
    int cnt = 0;
    for (int w = lane; w < NW; w += 64) cnt += __popcll(packed[(size_t)n * NW + w]);
#pragma unroll
    for (int off = 32; off > 0; off >>= 1) cnt += __shfl_down(cnt, off, 64);
    if (lane == 0) areaOrig[n] = (float)cnt;
}

// ---------------------------------------------------------------------------
// 3) Stable descending rank-sort by score (single block). Also zero pairCount.
__global__ void k_sort1(const float* __restrict__ scores, const int* __restrict__ labels,
                        const float* __restrict__ areaOrig, int* __restrict__ order,
                        float* __restrict__ scores_s, int* __restrict__ labels_s,
                        float* __restrict__ area_s, int* __restrict__ pairCount) {
    __shared__ float sS[N];
    int i = threadIdx.x;
    if (i == 0) *pairCount = 0;
    if (i < N) sS[i] = scores[i];
    __syncthreads();
    if (i < N) {
        float si = sS[i];
        int rank = 0;
        for (int j = 0; j < N; ++j) {
            float sj = sS[j];
            if (sj > si || (sj == si && j < i)) rank++;
        }
        order[rank] = i;            // stable: equal scores keep original index order
    }
    __syncthreads();
    if (i < N) {
        int o = order[i];
        scores_s[i] = sS[o];
        labels_s[i] = labels[o];
        area_s[i]   = areaOrig[o];
    }
}

// ---------------------------------------------------------------------------
// 4) Compact list of same-class pairs (i<j) in sorted order.
__global__ void k_pairs(const int* __restrict__ labels_s, int* __restrict__ pairCount,
                        int2* __restrict__ pairList) {
    int idx = blockIdx.x * blockDim.x + threadIdx.x;
    if (idx >= N * N) return;
    int i = idx / N, j = idx - i * N;
    if (i < j && labels_s[i] == labels_s[j]) {
        int p = atomicAdd(pairCount, 1);
        pairList[p] = make_int2(i, j);
    }
}

// ---------------------------------------------------------------------------
// 5) IoU per pair: AND + popcount over packed words, one wave per pair.
__global__ void k_iou(const ull* __restrict__ packed, const int* __restrict__ order,
                      const float* __restrict__ area_s, const int* __restrict__ pairCount,
                      const int2* __restrict__ pairList, float* __restrict__ iou) {
    int gwid  = (blockIdx.x * blockDim.x + threadIdx.x) >> 6;
    int lane  = threadIdx.x & 63;
    int nwav  = (gridDim.x * blockDim.x) >> 6;
    int np    = *pairCount;
    for (int p = gwid; p < np; p += nwav) {
        int2 pr = pairList[p];
        const ull* A = packed + (size_t)order[pr.x] * NW;
        const ull* B = packed + (size_t)order[pr.y] * NW;
        int cnt = 0;
        for (int w = lane; w < NW; w += 64) cnt += __popcll(A[w] & B[w]);
#pragma unroll
        for (int off = 32; off > 0; off >>= 1) cnt += __shfl_down(cnt, off, 64);
        if (lane == 0) {
            float inter = (float)cnt;                       // exact (< 2^24)
            float uni   = area_s[pr.x] + area_s[pr.y] - inter;
            iou[pr.x * N + pr.y] = inter / uni;
        }
    }
}

// ---------------------------------------------------------------------------
// 6) comp (column max), decay coefficient, decayed scores, stable re-sort,
//    emit scores/labels/keep_inds. Single block.
__global__ void k_decay(const int* __restrict__ labels_s, const float* __restrict__ iou,
                        const float* __restrict__ scores_s, const int* __restrict__ order,
                        float* __restrict__ outScores, float* __restrict__ outLabels,
                        float* __restrict__ outKeep, int* __restrict__ keepOrig) {
    __shared__ float compS[N];
    __shared__ int   labS[N];
    __shared__ float sdec[N];
    int j = threadIdx.x;
    if (j < N) labS[j] = labels_s[j];
    __syncthreads();
    if (j < N) {                                   // comp[j] = max_{i<j, same class} iou
        int lj = labS[j];
        float m = 0.f;
        for (int i = 0; i < j; ++i)
            if (labS[i] == lj) m = fmaxf(m, iou[i * N + j]);
        compS[j] = m;
    }
    __syncthreads();
    if (j < N) {                                   // coefficient
        int lj = labS[j];
        float c = 1.f;                             // row-0 / zero-iou rows bound the min at 1
        for (int i = 0; i < j; ++i) {
            if (labS[i] == lj) {
                float d  = iou[i * N + j];
                float ci = compS[i];
                float r  = expf(-2.f * d * d) / expf(-2.f * ci * ci);  // mirror np exactly
                c = fminf(c, r);
            }
        }
        sdec[j] = scores_s[j] * c;
    }
    __syncthreads();
    if (j < N) {                                   // stable descending rank on decayed scores
        float sj = sdec[j];
        int rank = 0;
        for (int i = 0; i < N; ++i) {
            float si = sdec[i];
            if (si > sj || (si == sj && i < j)) rank++;
        }
        int o = order[j];
        outScores[rank] = sj;
        outLabels[rank] = (float)labS[j];
        outKeep[rank]   = (float)o;
        keepOrig[rank]  = o;
    }
}

// ---------------------------------------------------------------------------
// 7) Expand kept masks from packed bits to float output (float4 stores).
__global__ void k_gather(const ull* __restrict__ packed, const int* __restrict__ keepOrig,
                         float4* __restrict__ outMasks) {
    int gid = blockIdx.x * blockDim.x + threadIdx.x;
    if (gid >= N * (HW / 4)) return;
    int k   = gid / (HW / 4);
    int q   = gid - k * (HW / 4);
    int pix = q * 4;
    int orig = keepOrig[k];
    ull w  = packed[(size_t)orig * NW + (pix >> 6)];
    int sh = pix & 63;
    float4 r;
    r.x = (float)((w >> (sh    )) & 1ULL);
    r.y = (float)((w >> (sh + 1)) & 1ULL);
    r.z = (float)((w >> (sh + 2)) & 1ULL);
    r.w = (float)((w >> (sh + 3)) & 1ULL);
    outMasks[gid] = r;
}

// ---------------------------------------------------------------------------
extern "C" void kernel_launch(void* const* d_in, const int* in_sizes, int n_in,
                              void* d_out, int out_size, void* d_ws, size_t ws_size,
                              hipStream_t stream) {
    const float* mask_preds = (const float*)d_in[0];
    const int*   labels     = (const int*)d_in[1];
    const float* scores     = (const float*)d_in[2];

    float* o         = (float*)d_out;
    float* outScores = o;
    float* outLabels = o + N;
    float* outMasks  = o + 2 * N;
    float* outKeep   = o + 2 * N + (size_t)N * HW;

    // workspace carve-up (all chunks 16B-aligned; total ~5.81 MB)
    char* w = (char*)d_ws;
    ull*   packed   = (ull*)w;    w += (size_t)N * NW * 8;       // 3,800,000
    float* areaOrig = (float*)w;  w += N * 4;                    // 2,000
    int*   order    = (int*)w;    w += N * 4;
    float* scores_s = (float*)w;  w += N * 4;
    int*   labels_s = (int*)w;    w += N * 4;
    float* area_s   = (float*)w;  w += N * 4;
    int*   keepOrig = (int*)w;    w += N * 4;
    int*   pairCount= (int*)w;    w += 16;
    int2*  pairList = (int2*)w;   w += (size_t)(N * (N - 1) / 2) * 8;  // 998,000
    float* iou      = (float*)w;  /* N*N*4 = 1,000,000 */

    hipLaunchKernelGGL(k_pack,  dim3((N * HW) / 256), dim3(256), 0, stream, mask_preds, packed);
    hipLaunchKernelGGL(k_area,  dim3(N), dim3(64), 0, stream, packed, areaOrig);
    hipLaunchKernelGGL(k_sort1, dim3(1), dim3(512), 0, stream,
                       scores, labels, areaOrig, order, scores_s, labels_s, area_s, pairCount);
    hipLaunchKernelGGL(k_pairs, dim3((N * N + 255) / 256), dim3(256), 0, stream,
                       labels_s, pairCount, pairList);
    hipLaunchKernelGGL(k_iou,   dim3(256), dim3(256), 0, stream,
                       packed, order, area_s, pairCount, pairList, iou);
    hipLaunchKernelGGL(k_decay, dim3(1), dim3(512), 0, stream,
                       labels_s, iou, scores_s, order, outScores, outLabels, outKeep, keepOrig);
    hipLaunchKernelGGL(k_gather, dim3((N * (HW / 4) + 255) / 256), dim3(256), 0, stream,
                       packed, keepOrig, (float4*)outMasks);
}

// Round 2
// 127.989 us; speedup vs baseline: 2.3839x; 2.3839x over previous
//
#include <hip/hip_runtime.h>

typedef unsigned long long ull;

constexpr int N  = 500;
constexpr int HW = 60800;   // 200*304
constexpr int NW = 950;     // HW/64 (exact)
constexpr int NC = 80;      // num classes

// ---------------------------------------------------------------------------
// 1) Binarize + bit-pack. One wave per 256-pixel tile: 4 coalesced scalar
//    loads (independent -> pipelined), 4 ballots, one 32B store from lane 0.
__global__ void k_pack(const float* __restrict__ mp, ull* __restrict__ packed) {
    int tile = blockIdx.x;                 // N*HW/256 tiles exactly
    int lane = threadIdx.x;                // block = 64 = 1 wave
    size_t base = (size_t)tile * 256;
    float v0 = mp[base +   0 + lane];
    float v1 = mp[base +  64 + lane];
    float v2 = mp[base + 128 + lane];
    float v3 = mp[base + 192 + lane];
    ull b0 = __ballot(v0 > 0.5f);
    ull b1 = __ballot(v1 > 0.5f);
    ull b2 = __ballot(v2 > 0.5f);
    ull b3 = __ballot(v3 > 0.5f);
    if (lane == 0) {
        longlong4 w;
        w.x = (long long)b0; w.y = (long long)b1; w.z = (long long)b2; w.w = (long long)b3;
        *(longlong4*)(packed + (base >> 6)) = w;
    }
}

// ---------------------------------------------------------------------------
// 2) Mask areas via popcount (one wave per instance).
__global__ void k_area(const ull* __restrict__ packed, float* __restrict__ areaOrig) {
    int n = blockIdx.x;
    int lane = threadIdx.x;
    int cnt = 0;
    for (int w = lane; w < NW; w += 64) cnt += __popcll(packed[(size_t)n * NW + w]);
#pragma unroll
    for (int off = 32; off > 0; off >>= 1) cnt += __shfl_down(cnt, off, 64);
    if (lane == 0) areaOrig[n] = (float)cnt;
}

// ---------------------------------------------------------------------------
// 3) Stable descending rank-sort by score (single block). Also zero pairCount.
__global__ void k_sort1(const float* __restrict__ scores, const int* __restrict__ labels,
                        const float* __restrict__ areaOrig, int* __restrict__ order,
                        float* __restrict__ scores_s, int* __restrict__ labels_s,
                        float* __restrict__ area_s, int* __restrict__ pairCount) {
    __shared__ float sS[N];
    int i = threadIdx.x;
    if (i == 0) *pairCount = 0;
    if (i < N) sS[i] = scores[i];
    __syncthreads();
    if (i < N) {
        float si = sS[i];
        int rank = 0;
        for (int j = 0; j < N; ++j) {
            float sj = sS[j];
            if (sj > si || (sj == si && j < i)) rank++;
        }
        order[rank] = i;            // stable: equal scores keep original index order
    }
    __syncthreads();
    if (i < N) {
        int o = order[i];
        scores_s[i] = sS[o];
        labels_s[i] = labels[o];
        area_s[i]   = areaOrig[o];
    }
}

// ---------------------------------------------------------------------------
// 4) Compact list of same-class pairs (i<j) in sorted order.
__global__ void k_pairs(const int* __restrict__ labels_s, int* __restrict__ pairCount,
                        int2* __restrict__ pairList) {
    int idx = blockIdx.x * blockDim.x + threadIdx.x;
    if (idx >= N * N) return;
    int i = idx / N, j = idx - i * N;
    if (i < j && labels_s[i] == labels_s[j]) {
        int p = atomicAdd(pairCount, 1);
        pairList[p] = make_int2(i, j);
    }
}

// ---------------------------------------------------------------------------
// 5) IoU per pair: AND + popcount over packed words, one wave per pair.
__global__ void k_iou(const ull* __restrict__ packed, const int* __restrict__ order,
                      const float* __restrict__ area_s, const int* __restrict__ pairCount,
                      const int2* __restrict__ pairList, float* __restrict__ iou) {
    int gwid  = (blockIdx.x * blockDim.x + threadIdx.x) >> 6;
    int lane  = threadIdx.x & 63;
    int nwav  = (gridDim.x * blockDim.x) >> 6;
    int np    = *pairCount;
    for (int p = gwid; p < np; p += nwav) {
        int2 pr = pairList[p];
        const ull* A = packed + (size_t)order[pr.x] * NW;
        const ull* B = packed + (size_t)order[pr.y] * NW;
        int cnt = 0;
        for (int w = lane; w < NW; w += 64) cnt += __popcll(A[w] & B[w]);
#pragma unroll
        for (int off = 32; off > 0; off >>= 1) cnt += __shfl_down(cnt, off, 64);
        if (lane == 0) {
            float inter = (float)cnt;                       // exact (< 2^24)
            float uni   = area_s[pr.x] + area_s[pr.y] - inter;
            iou[pr.x * N + pr.y] = inter / uni;
        }
    }
}

// ---------------------------------------------------------------------------
// 6) comp (column max), decay coefficient, decayed scores, stable re-sort.
//    Per-class CSR in LDS: each thread only visits its ~N/NC class members.
__global__ void k_decay(const int* __restrict__ labels_s, const float* __restrict__ iou,
                        const float* __restrict__ scores_s, const int* __restrict__ order,
                        float* __restrict__ outScores, float* __restrict__ outLabels,
                        float* __restrict__ outKeep, int* __restrict__ keepOrig) {
    __shared__ int   labS[N];
    __shared__ float compS[N];
    __shared__ float sdec[N];
    __shared__ int   cnt[NC];
    __shared__ int   offs[NC + 1];
    __shared__ int   members[N];
    int j = threadIdx.x;
    if (j < NC) cnt[j] = 0;
    if (j < N) labS[j] = labels_s[j];
    __syncthreads();
    if (j < N) atomicAdd(&cnt[labS[j]], 1);
    __syncthreads();
    if (j == 0) {
        int s = 0;
        for (int c = 0; c < NC; ++c) { offs[c] = s; s += cnt[c]; }
        offs[NC] = s;
    }
    __syncthreads();
    if (j < NC) cnt[j] = offs[j];          // running insertion cursors
    __syncthreads();
    if (j < N) { int p = atomicAdd(&cnt[labS[j]], 1); members[p] = j; }
    __syncthreads();
    if (j < N) {                            // comp[j] = max_{i<j, same class} iou[i,j]
        int lj = labS[j];
        float m = 0.f;
        int b = offs[lj], e = offs[lj + 1];
        for (int t = b; t < e; ++t) {
            int i = members[t];
            if (i < j) m = fmaxf(m, iou[i * N + j]);
        }
        compS[j] = m;
    }
    __syncthreads();
    if (j < N) {                            // coefficient (min over same-class preds; 1 bounds it)
        int lj = labS[j];
        float c = 1.f;
        int b = offs[lj], e = offs[lj + 1];
        for (int t = b; t < e; ++t) {
            int i = members[t];
            if (i < j) {
                float d  = iou[i * N + j];
                float ci = compS[i];
                c = fminf(c, expf(-2.f * d * d) / expf(-2.f * ci * ci));  // mirror np
            }
        }
        sdec[j] = scores_s[j] * c;
    }
    __syncthreads();
    if (j < N) {                            // stable descending rank on decayed scores
        float sj = sdec[j];
        int rank = 0;
        for (int i = 0; i < N; ++i) {
            float si = sdec[i];
            if (si > sj || (si == sj && i < j)) rank++;
        }
        int o = order[j];
        outScores[rank] = sj;
        outLabels[rank] = (float)labS[j];
        outKeep[rank]   = (float)o;
        keepOrig[rank]  = o;
    }
}

// ---------------------------------------------------------------------------
// 7) Expand kept masks from packed bits to float output (float4 stores).
__global__ void k_gather(const ull* __restrict__ packed, const int* __restrict__ keepOrig,
                         float4* __restrict__ outMasks) {
    int gid = blockIdx.x * blockDim.x + threadIdx.x;
    if (gid >= N * (HW / 4)) return;
    int k   = gid / (HW / 4);
    int q   = gid - k * (HW / 4);
    int pix = q * 4;
    int orig = keepOrig[k];
    ull w  = packed[(size_t)orig * NW + (pix >> 6)];
    int sh = pix & 63;
    float4 r;
    r.x = (float)((w >> (sh    )) & 1ULL);
    r.y = (float)((w >> (sh + 1)) & 1ULL);
    r.z = (float)((w >> (sh + 2)) & 1ULL);
    r.w = (float)((w >> (sh + 3)) & 1ULL);
    outMasks[gid] = r;
}

// ---------------------------------------------------------------------------
extern "C" void kernel_launch(void* const* d_in, const int* in_sizes, int n_in,
                              void* d_out, int out_size, void* d_ws, size_t ws_size,
                              hipStream_t stream) {
    const float* mask_preds = (const float*)d_in[0];
    const int*   labels     = (const int*)d_in[1];
    const float* scores     = (const float*)d_in[2];

    float* o         = (float*)d_out;
    float* outScores = o;
    float* outLabels = o + N;
    float* outMasks  = o + 2 * N;
    float* outKeep   = o + 2 * N + (size_t)N * HW;

    // workspace carve-up (all chunks 16B-aligned; total ~5.81 MB)
    char* w = (char*)d_ws;
    ull*   packed   = (ull*)w;    w += (size_t)N * NW * 8;       // 3,800,000
    float* areaOrig = (float*)w;  w += N * 4;                    // 2,000
    int*   order    = (int*)w;    w += N * 4;
    float* scores_s = (float*)w;  w += N * 4;
    int*   labels_s = (int*)w;    w += N * 4;
    float* area_s   = (float*)w;  w += N * 4;
    int*   keepOrig = (int*)w;    w += N * 4;
    int*   pairCount= (int*)w;    w += 16;
    int2*  pairList = (int2*)w;   w += (size_t)(N * (N - 1) / 2) * 8;  // 998,000
    float* iou      = (float*)w;  /* N*N*4 = 1,000,000 */

    hipLaunchKernelGGL(k_pack,  dim3((N * HW) / 256), dim3(64), 0, stream, mask_preds, packed);
    hipLaunchKernelGGL(k_area,  dim3(N), dim3(64), 0, stream, packed, areaOrig);
    hipLaunchKernelGGL(k_sort1, dim3(1), dim3(512), 0, stream,
                       scores, labels, areaOrig, order, scores_s, labels_s, area_s, pairCount);
    hipLaunchKernelGGL(k_pairs, dim3((N * N + 255) / 256), dim3(256), 0, stream,
                       labels_s, pairCount, pairList);
    hipLaunchKernelGGL(k_iou,   dim3(256), dim3(256), 0, stream,
                       packed, order, area_s, pairCount, pairList, iou);
    hipLaunchKernelGGL(k_decay, dim3(1), dim3(512), 0, stream,
                       labels_s, iou, scores_s, order, outScores, outLabels, outKeep, keepOrig);
    hipLaunchKernelGGL(k_gather, dim3((N * (HW / 4) + 255) / 256), dim3(256), 0, stream,
                       packed, keepOrig, (float4*)outMasks);
}